// Round 6
// baseline (55852.649 us; speedup 1.0000x reference)
//
#include <hip/hip_runtime.h>
#include <math.h>

// LSTMEncoder: B=64,S=512,F=128,D=512,U=1024
// Persistent cooperative-style kernel, all 512 steps, flag-array grid barrier
// (parallel stores + parallel spins; no atomic RMW serialization).
// z = bf + x_t@Wf + h@Wh (gate-packed W4[k][u][4]); gates i,f,g,o; c in regs.

#define BB 64
#define SS 512
#define FF 128
#define DD 512
#define UU 1024
#define GG 4096  // 4*U
#define NBLK 256

__device__ __forceinline__ float sigmoidf_(float v) {
    return 1.0f / (1.0f + __expf(-v));
}
__device__ __forceinline__ float tanhf_(float v) {
    float e = __expf(2.0f * v);          // inf-safe: 1 - 2/(e+1)
    return 1.0f - 2.0f / (e + 1.0f);
}

// Wf4[f][u][gate] = sum_d dense_W[f][d] * Wx[d][gate*UU+u]
__global__ __launch_bounds__(256) void fuse_w(const float* __restrict__ dW,
                                              const float* __restrict__ Wx,
                                              float* __restrict__ Wf4) {
    int tid = blockIdx.x * 256 + threadIdx.x;   // 128*4096
    int gcol = tid & (GG - 1);
    int f = tid >> 12;
    const float* wr = dW + f * DD;
    float acc = 0.0f;
#pragma unroll 4
    for (int d = 0; d < DD; ++d)
        acc = fmaf(wr[d], Wx[(size_t)d * GG + gcol], acc);
    Wf4[((size_t)f * UU + (gcol & (UU - 1))) * 4 + (gcol >> 10)] = acc;
}

// bf[g] = sum_d dense_b[d] * Wx[d][g] + b[g]   (gate-major [4][UU])
__global__ __launch_bounds__(256) void fuse_b(const float* __restrict__ db,
                                              const float* __restrict__ Wx,
                                              const float* __restrict__ bias,
                                              float* __restrict__ bf) {
    int g = blockIdx.x * 256 + threadIdx.x;     // 4096
    float acc = bias[g];
#pragma unroll 4
    for (int d = 0; d < DD; ++d)
        acc = fmaf(db[d], Wx[(size_t)d * GG + g], acc);
    bf[g] = acc;
}

// Wh[k][gate*UU+u] -> Wh4[k][u][gate]
__global__ __launch_bounds__(256) void repack_wh(const float* __restrict__ Wh,
                                                 float* __restrict__ Wh4) {
    size_t tid = (size_t)blockIdx.x * 256 + threadIdx.x;   // 4M
    int gcol = (int)(tid & (GG - 1));
    int k = (int)(tid >> 12);
    Wh4[((size_t)k * UU + (gcol & (UU - 1))) * 4 + (gcol >> 10)] = Wh[tid];
}

// x[b][s][k] -> xT[s][k][b]
__global__ __launch_bounds__(256) void transpose_x(const float* __restrict__ x,
                                                   float* __restrict__ xT) {
    __shared__ float xs[64 * 129];
    const int s = blockIdx.x;                    // 0..511
    for (int i = threadIdx.x; i < 64 * 128; i += 256) {
        int b = i >> 7, k = i & 127;
        xs[b * 129 + k] = x[((size_t)b * SS + s) * FF + k];
    }
    __syncthreads();
    for (int i = threadIdx.x; i < 64 * 128; i += 256) {
        int k = i >> 6, b = i & 63;
        xT[((size_t)s * FF + k) * 64 + b] = xs[b * 129 + k];
    }
}

__device__ __forceinline__ void fma16(float (&acc)[4][4], float4 h4, float4 w4) {
    acc[0][0] = fmaf(h4.x, w4.x, acc[0][0]);
    acc[0][1] = fmaf(h4.x, w4.y, acc[0][1]);
    acc[0][2] = fmaf(h4.x, w4.z, acc[0][2]);
    acc[0][3] = fmaf(h4.x, w4.w, acc[0][3]);
    acc[1][0] = fmaf(h4.y, w4.x, acc[1][0]);
    acc[1][1] = fmaf(h4.y, w4.y, acc[1][1]);
    acc[1][2] = fmaf(h4.y, w4.z, acc[1][2]);
    acc[1][3] = fmaf(h4.y, w4.w, acc[1][3]);
    acc[2][0] = fmaf(h4.z, w4.x, acc[2][0]);
    acc[2][1] = fmaf(h4.z, w4.y, acc[2][1]);
    acc[2][2] = fmaf(h4.z, w4.z, acc[2][2]);
    acc[2][3] = fmaf(h4.z, w4.w, acc[2][3]);
    acc[3][0] = fmaf(h4.w, w4.x, acc[3][0]);
    acc[3][1] = fmaf(h4.w, w4.y, acc[3][1]);
    acc[3][2] = fmaf(h4.w, w4.z, acc[3][2]);
    acc[3][3] = fmaf(h4.w, w4.w, acc[3][3]);
}

// Flag-array grid barrier, generation = t+1 (monotonic; flags zeroed per launch).
// Arrive: one relaxed device-scope store per block (parallel across blocks).
// Observe: threads 0..255 each spin on one block's flag (parallel loads).
__device__ __forceinline__ void grid_barrier(unsigned* flags, int t) {
    __syncthreads();                 // all block work done (incl. vmcnt drain)
    if (threadIdx.x == 0) {
        __threadfence();             // release: h stores visible device-wide
        __hip_atomic_store(&flags[blockIdx.x * 4], (unsigned)(t + 1),
                           __ATOMIC_RELAXED, __HIP_MEMORY_SCOPE_AGENT);
    }
    if (threadIdx.x < NBLK) {
        while (__hip_atomic_load(&flags[threadIdx.x * 4],
                                 __ATOMIC_RELAXED, __HIP_MEMORY_SCOPE_AGENT)
               < (unsigned)(t + 1))
            __builtin_amdgcn_s_sleep(1);
    }
    __syncthreads();
    __threadfence();                 // acquire: stale caches invalidated
}

// Persistent kernel: 256 blocks x 1024 thr (16 waves, 4/SIMD, 1 block/CU).
// Block = (utile 16u, btile 16b); wave = 64-k slice of h-K + 8-k slice of x-K.
// Lane: u_l=lane&15, bgrp=lane>>4 (4 b's). acc[b][gate]; gate-packed float4 weights.
__global__ __launch_bounds__(1024, 4) void lstm_persist(
    const float* __restrict__ xT,     // [SS][FF][64]
    const float* __restrict__ Wh4,    // [1024k][1024u][4]
    const float* __restrict__ Wf4,    // [128k][1024u][4]
    const float* __restrict__ bfb,    // [4][1024]
    float* __restrict__ out,          // [64][512][1024]
    float* h0, float* h1,             // parity buffers [1024k][64b]
    unsigned* flags) {
    __shared__ float zl[16 * 1024];   // 64 KB: [wave][idx16][lane64] - conflict-free
    __shared__ float zr[1024];        // 4 KB

    const int utile = blockIdx.x & 63;
    const int btile = blockIdx.x >> 6;
    const int u0 = utile * 16;
    const int wid  = threadIdx.x >> 6;
    const int lane = threadIdx.x & 63;
    const int u_l  = lane & 15;
    const int bgrp = lane >> 4;
    const int bbase = btile * 16 + bgrp * 4;

    const float* wfx = Wf4 + ((size_t)(wid * 8) * UU + u0 + u_l) * 4;
    const float* whb = Wh4 + ((size_t)(wid * 64) * UU + u0 + u_l) * 4;

    float creg = 0.0f;                // stage-2 thread's cell state (fixed (b,u))

    for (int t = 0; t < SS; ++t) {
        const float* hprev = (t & 1) ? h0 : h1;
        float* hnext       = (t & 1) ? h1 : h0;

        float acc[4][4];
#pragma unroll
        for (int i = 0; i < 4; ++i)
#pragma unroll
            for (int g = 0; g < 4; ++g) acc[i][g] = 0.0f;

        // x part: k in [wid*8, wid*8+8)  (8-deep load batch)
        {
            const float* xp = xT + ((size_t)t * FF + wid * 8) * 64 + bbase;
            const float* wp = wfx;
            float4 hb[8], wb[8];
#pragma unroll
            for (int j = 0; j < 8; ++j) {
                hb[j] = *(const float4*)(xp + j * 64);
                wb[j] = *(const float4*)(wp + (size_t)j * UU * 4);
            }
#pragma unroll
            for (int j = 0; j < 8; ++j) fma16(acc, hb[j], wb[j]);
        }
        // h part: k in [wid*64, wid*64+64), batches of 8
        if (t > 0) {
            const float* hp = hprev + (size_t)(wid * 64) * 64 + bbase;
            const float* wp = whb;
            for (int kk = 0; kk < 64; kk += 8) {
                float4 hb[8], wb[8];
#pragma unroll
                for (int j = 0; j < 8; ++j) {
                    hb[j] = *(const float4*)(hp + j * 64);
                    wb[j] = *(const float4*)(wp + (size_t)j * UU * 4);
                }
#pragma unroll
                for (int j = 0; j < 8; ++j) fma16(acc, hb[j], wb[j]);
                hp += 8 * 64;
                wp += (size_t)8 * UU * 4;
            }
        }

        // partials -> LDS, lane-stride-1 (conflict-free scalar stores)
#pragma unroll
        for (int i = 0; i < 4; ++i)
#pragma unroll
            for (int g = 0; g < 4; ++g)
                zl[wid * 1024 + (i * 4 + g) * 64 + lane] = acc[i][g];
        __syncthreads();

        // 16-way reduce, stride-1 reads
        {
            float v = 0.0f;
#pragma unroll
            for (int w = 0; w < 16; ++w) v += zl[w * 1024 + threadIdx.x];
            zr[threadIdx.x] = v;
        }
        __syncthreads();

        // stage 2: 256 threads -> one (b,u); gates + state
        if (threadIdx.x < 256) {
            const int bl = threadIdx.x >> 4;    // 0..15
            const int ul = threadIdx.x & 15;
            const int bb = btile * 16 + bl;
            const int uu = u0 + ul;
            const int ii = bl & 3;              // b-within-group
            const int bg = bl >> 2;             // bgrp
            const int ln = bg * 16 + ul;        // producing lane

            float z0 = zr[(ii * 4 + 0) * 64 + ln] + bfb[uu];
            float z1 = zr[(ii * 4 + 1) * 64 + ln] + bfb[uu + UU];
            float z2 = zr[(ii * 4 + 2) * 64 + ln] + bfb[uu + 2 * UU];
            float z3 = zr[(ii * 4 + 3) * 64 + ln] + bfb[uu + 3 * UU];

            float iv = sigmoidf_(z0);
            float fv = sigmoidf_(z1);
            float gv = tanhf_(z2);
            float ov = sigmoidf_(z3);

            creg = fv * creg + iv * gv;
            float hv = ov * tanhf_(creg);

            out[((size_t)bb * SS + t) * UU + uu] = hv;
            hnext[(size_t)uu * 64 + bb] = hv;
        }

        if (t != SS - 1) grid_barrier(flags, t);
    }
}

extern "C" void kernel_launch(void* const* d_in, const int* in_sizes, int n_in,
                              void* d_out, int out_size, void* d_ws, size_t ws_size,
                              hipStream_t stream) {
    const float* x    = (const float*)d_in[0];   // [64,512,128]
    const float* dW   = (const float*)d_in[1];   // [128,512]
    const float* db   = (const float*)d_in[2];   // [512]
    const float* Wx   = (const float*)d_in[3];   // [512,4096]
    const float* Wh   = (const float*)d_in[4];   // [1024,4096]
    const float* bias = (const float*)d_in[5];   // [4096]
    float* out = (float*)d_out;                  // [64,512,1024]

    char* ws = (char*)d_ws;
    size_t off = 0;
    float* Wh4 = (float*)(ws + off); off += (size_t)UU * UU * 4 * 4;   // 16 MB
    float* xT  = (float*)(ws + off); off += (size_t)SS * FF * 64 * 4;  // 16 MB
    float* Wf4 = (float*)(ws + off); off += (size_t)FF * UU * 4 * 4;   // 2 MB
    float* bf  = (float*)(ws + off); off += (size_t)GG * 4;            // 16 KB
    float* h0  = (float*)(ws + off); off += (size_t)BB * UU * 4;       // 256 KB
    float* h1  = (float*)(ws + off); off += (size_t)BB * UU * 4;       // 256 KB
    unsigned* flags = (unsigned*)(ws + off);                           // 4 KB (256*16B)

    hipMemsetAsync(flags, 0, NBLK * 4 * sizeof(unsigned), stream);
    fuse_w<<<(FF * GG) / 256, 256, 0, stream>>>(dW, Wx, Wf4);
    fuse_b<<<GG / 256, 256, 0, stream>>>(db, Wx, bias, bf);
    repack_wh<<<(UU * GG) / 256, 256, 0, stream>>>(Wh, Wh4);
    transpose_x<<<SS, 256, 0, stream>>>(x, xT);

    void* args[] = {(void*)&xT, (void*)&Wh4, (void*)&Wf4, (void*)&bf, (void*)&out,
                    (void*)&h0, (void*)&h1, (void*)&flags};
    hipLaunchCooperativeKernel((void*)lstm_persist, dim3(NBLK), dim3(1024), args, 0, stream);
}

// Round 7
// 24018.468 us; speedup vs baseline: 2.3254x; 2.3254x over previous
//
#include <hip/hip_runtime.h>
#include <math.h>

// LSTMEncoder: B=64,S=512,F=128,D=512,U=1024
// Persistent kernel, all 512 steps. Sync is per-btile-group (64 blocks sharing
// 16 batch rows) via flag arrays accessed with agent-scope RELAXED atomics
// (sc1: cache-bypassing, fence-free -> L2 weight residency preserved).
// h exchanged through sc1 loads/stores; weights/x/bias normal cached loads.
// z = bf + x_t@Wf + h@Wh (gate-packed W4[k][u][4]); gates i,f,g,o; c in regs.

#define BB 64
#define SS 512
#define FF 128
#define DD 512
#define UU 1024
#define GG 4096  // 4*U
#define NBLK 256

__device__ __forceinline__ float sigmoidf_(float v) {
    return 1.0f / (1.0f + __expf(-v));
}
__device__ __forceinline__ float tanhf_(float v) {
    float e = __expf(2.0f * v);          // inf-safe: 1 - 2/(e+1)
    return 1.0f - 2.0f / (e + 1.0f);
}

// Wf4[f][u][gate] = sum_d dense_W[f][d] * Wx[d][gate*UU+u]
__global__ __launch_bounds__(256) void fuse_w(const float* __restrict__ dW,
                                              const float* __restrict__ Wx,
                                              float* __restrict__ Wf4) {
    int tid = blockIdx.x * 256 + threadIdx.x;   // 128*4096
    int gcol = tid & (GG - 1);
    int f = tid >> 12;
    const float* wr = dW + f * DD;
    float acc = 0.0f;
#pragma unroll 4
    for (int d = 0; d < DD; ++d)
        acc = fmaf(wr[d], Wx[(size_t)d * GG + gcol], acc);
    Wf4[((size_t)f * UU + (gcol & (UU - 1))) * 4 + (gcol >> 10)] = acc;
}

// bf[g] = sum_d dense_b[d] * Wx[d][g] + b[g]   (gate-major [4][UU])
__global__ __launch_bounds__(256) void fuse_b(const float* __restrict__ db,
                                              const float* __restrict__ Wx,
                                              const float* __restrict__ bias,
                                              float* __restrict__ bf) {
    int g = blockIdx.x * 256 + threadIdx.x;     // 4096
    float acc = bias[g];
#pragma unroll 4
    for (int d = 0; d < DD; ++d)
        acc = fmaf(db[d], Wx[(size_t)d * GG + g], acc);
    bf[g] = acc;
}

// Wh[k][gate*UU+u] -> Wh4[k][u][gate]
__global__ __launch_bounds__(256) void repack_wh(const float* __restrict__ Wh,
                                                 float* __restrict__ Wh4) {
    size_t tid = (size_t)blockIdx.x * 256 + threadIdx.x;   // 4M
    int gcol = (int)(tid & (GG - 1));
    int k = (int)(tid >> 12);
    Wh4[((size_t)k * UU + (gcol & (UU - 1))) * 4 + (gcol >> 10)] = Wh[tid];
}

// x[b][s][k] -> xT[s][k][b]
__global__ __launch_bounds__(256) void transpose_x(const float* __restrict__ x,
                                                   float* __restrict__ xT) {
    __shared__ float xs[64 * 129];
    const int s = blockIdx.x;                    // 0..511
    for (int i = threadIdx.x; i < 64 * 128; i += 256) {
        int b = i >> 7, k = i & 127;
        xs[b * 129 + k] = x[((size_t)b * SS + s) * FF + k];
    }
    __syncthreads();
    for (int i = threadIdx.x; i < 64 * 128; i += 256) {
        int k = i >> 6, b = i & 63;
        xT[((size_t)s * FF + k) * 64 + b] = xs[b * 129 + k];
    }
}

__device__ __forceinline__ void fma16(float (&acc)[4][4], float4 h4, float4 w4) {
    acc[0][0] = fmaf(h4.x, w4.x, acc[0][0]);
    acc[0][1] = fmaf(h4.x, w4.y, acc[0][1]);
    acc[0][2] = fmaf(h4.x, w4.z, acc[0][2]);
    acc[0][3] = fmaf(h4.x, w4.w, acc[0][3]);
    acc[1][0] = fmaf(h4.y, w4.x, acc[1][0]);
    acc[1][1] = fmaf(h4.y, w4.y, acc[1][1]);
    acc[1][2] = fmaf(h4.y, w4.z, acc[1][2]);
    acc[1][3] = fmaf(h4.y, w4.w, acc[1][3]);
    acc[2][0] = fmaf(h4.z, w4.x, acc[2][0]);
    acc[2][1] = fmaf(h4.z, w4.y, acc[2][1]);
    acc[2][2] = fmaf(h4.z, w4.z, acc[2][2]);
    acc[2][3] = fmaf(h4.z, w4.w, acc[2][3]);
    acc[3][0] = fmaf(h4.w, w4.x, acc[3][0]);
    acc[3][1] = fmaf(h4.w, w4.y, acc[3][1]);
    acc[3][2] = fmaf(h4.w, w4.z, acc[3][2]);
    acc[3][3] = fmaf(h4.w, w4.w, acc[3][3]);
}

// Persistent kernel: 256 blocks x 1024 thr (16 waves, 4/SIMD).
// Block = (utile=blockIdx&63 -> 16 u, btile=blockIdx>>6 -> 16 b).
// XCD = utile%8 -> per-XCD weight slice 2.2MB, L2-resident (normal loads).
// Sync group = 64 blocks sharing btile. flags[btile][utile], gen = steps done.
// All cross-block data (h, flags) via agent-relaxed atomics (sc1, fence-free).
__global__ __launch_bounds__(1024, 4) void lstm_persist(
    const float* __restrict__ xT,     // [SS][FF][64]
    const float* __restrict__ Wh4,    // [1024k][1024u][4]
    const float* __restrict__ Wf4,    // [128k][1024u][4]
    const float* __restrict__ bfb,    // [4][1024]
    float* __restrict__ out,          // [64][512][1024]
    float* h0, float* h1,             // parity buffers [1024k][64b]
    unsigned* flags) {                // [4 btile][64 utile]
    __shared__ float zl[16 * 1024];   // 64 KB [wave][idx16][lane64] conflict-free
    __shared__ float zr[1024];        // 4 KB

    const int utile = blockIdx.x & 63;
    const int btile = blockIdx.x >> 6;
    const int u0 = utile * 16;
    const int wid  = threadIdx.x >> 6;
    const int lane = threadIdx.x & 63;
    const int u_l  = lane & 15;
    const int bgrp = lane >> 4;
    const int bbase = btile * 16 + bgrp * 4;

    const float* wfx = Wf4 + ((size_t)(wid * 8) * UU + u0 + u_l) * 4;
    const float* whb = Wh4 + ((size_t)(wid * 64) * UU + u0 + u_l) * 4;
    unsigned* myflag = &flags[btile * 64 + utile];
    unsigned* gflags = &flags[btile * 64];

    // stage-2 per-thread constants (thread < 256 owns one (b,u))
    float bz0 = 0, bz1 = 0, bz2 = 0, bz3 = 0, creg = 0.0f;
    int s2_zi = 0, s2_hi = 0;
    size_t s2_ob = 0;
    if (threadIdx.x < 256) {
        const int bl = threadIdx.x >> 4, ul = threadIdx.x & 15;
        const int bb = btile * 16 + bl, uu = u0 + ul;
        bz0 = bfb[uu];  bz1 = bfb[uu + UU];
        bz2 = bfb[uu + 2 * UU];  bz3 = bfb[uu + 3 * UU];
        s2_zi = ((bl & 3) * 4) * 64 + (bl >> 2) * 16 + ul;  // zr[(ii*4+g)*64+ln]
        s2_hi = uu * 64 + bb;
        s2_ob = (size_t)bb * SS + 0;   // + t per step, *UU + uu
        s2_ob = ((size_t)bb * SS) * UU + uu;
    }

    for (int t = 0; t < SS; ++t) {
        const float* hprev = (t & 1) ? h0 : h1;
        float* hnext       = (t & 1) ? h1 : h0;

        float acc[4][4];
#pragma unroll
        for (int i = 0; i < 4; ++i)
#pragma unroll
            for (int g = 0; g < 4; ++g) acc[i][g] = 0.0f;

        // ---- x part (no cross-block dependency; overlaps sync shadow) ----
        {
            const float* xp = xT + ((size_t)t * FF + wid * 8) * 64 + bbase;
            const float* wp = wfx;
            float4 hb[8], wb[8];
#pragma unroll
            for (int j = 0; j < 8; ++j) {
                hb[j] = *(const float4*)(xp + j * 64);
                wb[j] = *(const float4*)(wp + (size_t)j * UU * 4);
            }
#pragma unroll
            for (int j = 0; j < 8; ++j) fma16(acc, hb[j], wb[j]);
        }

        if (t > 0) {
            // ---- group sync: wave 0 polls 64 flags (4 lines, sc1) ----
            if (threadIdx.x < 64) {
                while (__hip_atomic_load(&gflags[threadIdx.x], __ATOMIC_RELAXED,
                                         __HIP_MEMORY_SCOPE_AGENT) < (unsigned)t)
                    __builtin_amdgcn_s_sleep(2);
            }
            __syncthreads();

            // ---- h part: k in [wid*64, wid*64+64), sc1 dword loads ----
            const float* hp = hprev + (size_t)(wid * 64) * 64 + bbase;
            const float* wp = whb;
            for (int kk = 0; kk < 64; kk += 8) {
                float4 wb[8];
                float hb[8][4];
#pragma unroll
                for (int j = 0; j < 8; ++j) {
                    wb[j] = *(const float4*)(wp + (size_t)j * UU * 4);
                    const float* hj = hp + j * 64;
#pragma unroll
                    for (int q = 0; q < 4; ++q)
                        hb[j][q] = __hip_atomic_load(hj + q, __ATOMIC_RELAXED,
                                                     __HIP_MEMORY_SCOPE_AGENT);
                }
#pragma unroll
                for (int j = 0; j < 8; ++j)
                    fma16(acc, make_float4(hb[j][0], hb[j][1], hb[j][2], hb[j][3]), wb[j]);
                hp += 8 * 64;
                wp += (size_t)8 * UU * 4;
            }
        }

        // ---- partials -> LDS, lane-stride-1 (conflict-free) ----
#pragma unroll
        for (int i = 0; i < 4; ++i)
#pragma unroll
            for (int g = 0; g < 4; ++g)
                zl[wid * 1024 + (i * 4 + g) * 64 + lane] = acc[i][g];
        __syncthreads();

        {
            float v = 0.0f;
#pragma unroll
            for (int w = 0; w < 16; ++w) v += zl[w * 1024 + threadIdx.x];
            zr[threadIdx.x] = v;
        }
        __syncthreads();

        // ---- stage 2: gates + state; h store via sc1 ----
        if (threadIdx.x < 256) {
            float z0 = zr[s2_zi + 0 * 64] + bz0;
            float z1 = zr[s2_zi + 1 * 64] + bz1;
            float z2 = zr[s2_zi + 2 * 64] + bz2;
            float z3 = zr[s2_zi + 3 * 64] + bz3;

            float iv = sigmoidf_(z0);
            float fv = sigmoidf_(z1);
            float gv = tanhf_(z2);
            float ov = sigmoidf_(z3);

            creg = fv * creg + iv * gv;
            float hv = ov * tanhf_(creg);

            out[s2_ob + (size_t)t * UU] = hv;
            __hip_atomic_store(&hnext[s2_hi], hv, __ATOMIC_RELAXED,
                               __HIP_MEMORY_SCOPE_AGENT);
        }

        // ---- arrive: syncthreads drains vmcnt (h stores done), then 1 store ----
        if (t != SS - 1) {
            __syncthreads();
            if (threadIdx.x == 0)
                __hip_atomic_store(myflag, (unsigned)(t + 1), __ATOMIC_RELAXED,
                                   __HIP_MEMORY_SCOPE_AGENT);
        }
    }
}

extern "C" void kernel_launch(void* const* d_in, const int* in_sizes, int n_in,
                              void* d_out, int out_size, void* d_ws, size_t ws_size,
                              hipStream_t stream) {
    const float* x    = (const float*)d_in[0];   // [64,512,128]
    const float* dW   = (const float*)d_in[1];   // [128,512]
    const float* db   = (const float*)d_in[2];   // [512]
    const float* Wx   = (const float*)d_in[3];   // [512,4096]
    const float* Wh   = (const float*)d_in[4];   // [1024,4096]
    const float* bias = (const float*)d_in[5];   // [4096]
    float* out = (float*)d_out;                  // [64,512,1024]

    char* ws = (char*)d_ws;
    size_t off = 0;
    float* Wh4 = (float*)(ws + off); off += (size_t)UU * UU * 4 * 4;   // 16 MB
    float* xT  = (float*)(ws + off); off += (size_t)SS * FF * 64 * 4;  // 16 MB
    float* Wf4 = (float*)(ws + off); off += (size_t)FF * UU * 4 * 4;   // 2 MB
    float* bf  = (float*)(ws + off); off += (size_t)GG * 4;            // 16 KB
    float* h0  = (float*)(ws + off); off += (size_t)BB * UU * 4;       // 256 KB
    float* h1  = (float*)(ws + off); off += (size_t)BB * UU * 4;       // 256 KB
    unsigned* flags = (unsigned*)(ws + off);                           // 1 KB

    hipMemsetAsync(flags, 0, 4 * 64 * sizeof(unsigned), stream);
    fuse_w<<<(FF * GG) / 256, 256, 0, stream>>>(dW, Wx, Wf4);
    fuse_b<<<GG / 256, 256, 0, stream>>>(db, Wx, bias, bf);
    repack_wh<<<(UU * GG) / 256, 256, 0, stream>>>(Wh, Wh4);
    transpose_x<<<SS, 256, 0, stream>>>(x, xT);

    void* args[] = {(void*)&xT, (void*)&Wh4, (void*)&Wf4, (void*)&bf, (void*)&out,
                    (void*)&h0, (void*)&h1, (void*)&flags};
    hipLaunchCooperativeKernel((void*)lstm_persist, dim3(NBLK), dim3(1024), args, 0, stream);
}

// Round 8
// 19034.990 us; speedup vs baseline: 2.9342x; 1.2618x over previous
//
#include <hip/hip_runtime.h>
#include <math.h>

// LSTMEncoder: B=64,S=512,F=128,D=512,U=1024
// Persistent kernel, all 512 steps. h is exchanged THROUGH `out` itself:
// producer writes out[b][t][u] with sc1 (write-through to MALL, no L2 alloc);
// consumers read out[*][t-1][*] with NORMAL cached loads — every h address is
// written exactly once per launch, so cached reads can never be stale.
// Sync: per-btile group (64 blocks) flag array, sc1 relaxed loads/stores only.
// z = bf + x_t@Wf + h@Wh (gate-packed W4[k][u][4]); gates i,f,g,o; c in regs.

#define BB 64
#define SS 512
#define FF 128
#define DD 512
#define UU 1024
#define GG 4096  // 4*U
#define NBLK 256

__device__ __forceinline__ float sigmoidf_(float v) {
    return 1.0f / (1.0f + __expf(-v));
}
__device__ __forceinline__ float tanhf_(float v) {
    float e = __expf(2.0f * v);          // inf-safe: 1 - 2/(e+1)
    return 1.0f - 2.0f / (e + 1.0f);
}

// Wf4[f][u][gate] = sum_d dense_W[f][d] * Wx[d][gate*UU+u]
__global__ __launch_bounds__(256) void fuse_w(const float* __restrict__ dW,
                                              const float* __restrict__ Wx,
                                              float* __restrict__ Wf4) {
    int tid = blockIdx.x * 256 + threadIdx.x;   // 128*4096
    int gcol = tid & (GG - 1);
    int f = tid >> 12;
    const float* wr = dW + f * DD;
    float acc = 0.0f;
#pragma unroll 4
    for (int d = 0; d < DD; ++d)
        acc = fmaf(wr[d], Wx[(size_t)d * GG + gcol], acc);
    Wf4[((size_t)f * UU + (gcol & (UU - 1))) * 4 + (gcol >> 10)] = acc;
}

// bf[g] = sum_d dense_b[d] * Wx[d][g] + b[g]   (gate-major [4][UU])
__global__ __launch_bounds__(256) void fuse_b(const float* __restrict__ db,
                                              const float* __restrict__ Wx,
                                              const float* __restrict__ bias,
                                              float* __restrict__ bf) {
    int g = blockIdx.x * 256 + threadIdx.x;     // 4096
    float acc = bias[g];
#pragma unroll 4
    for (int d = 0; d < DD; ++d)
        acc = fmaf(db[d], Wx[(size_t)d * GG + g], acc);
    bf[g] = acc;
}

// Wh[k][gate*UU+u] -> Wh4[k][u][gate]
__global__ __launch_bounds__(256) void repack_wh(const float* __restrict__ Wh,
                                                 float* __restrict__ Wh4) {
    size_t tid = (size_t)blockIdx.x * 256 + threadIdx.x;   // 4M
    int gcol = (int)(tid & (GG - 1));
    int k = (int)(tid >> 12);
    Wh4[((size_t)k * UU + (gcol & (UU - 1))) * 4 + (gcol >> 10)] = Wh[tid];
}

// x[b][s][k] -> xT[s][k][b]
__global__ __launch_bounds__(256) void transpose_x(const float* __restrict__ x,
                                                   float* __restrict__ xT) {
    __shared__ float xs[64 * 129];
    const int s = blockIdx.x;                    // 0..511
    for (int i = threadIdx.x; i < 64 * 128; i += 256) {
        int b = i >> 7, k = i & 127;
        xs[b * 129 + k] = x[((size_t)b * SS + s) * FF + k];
    }
    __syncthreads();
    for (int i = threadIdx.x; i < 64 * 128; i += 256) {
        int k = i >> 6, b = i & 63;
        xT[((size_t)s * FF + k) * 64 + b] = xs[b * 129 + k];
    }
}

__device__ __forceinline__ void fma16(float (&acc)[4][4], float4 h4, float4 w4) {
    acc[0][0] = fmaf(h4.x, w4.x, acc[0][0]);
    acc[0][1] = fmaf(h4.x, w4.y, acc[0][1]);
    acc[0][2] = fmaf(h4.x, w4.z, acc[0][2]);
    acc[0][3] = fmaf(h4.x, w4.w, acc[0][3]);
    acc[1][0] = fmaf(h4.y, w4.x, acc[1][0]);
    acc[1][1] = fmaf(h4.y, w4.y, acc[1][1]);
    acc[1][2] = fmaf(h4.y, w4.z, acc[1][2]);
    acc[1][3] = fmaf(h4.y, w4.w, acc[1][3]);
    acc[2][0] = fmaf(h4.z, w4.x, acc[2][0]);
    acc[2][1] = fmaf(h4.z, w4.y, acc[2][1]);
    acc[2][2] = fmaf(h4.z, w4.z, acc[2][2]);
    acc[2][3] = fmaf(h4.z, w4.w, acc[2][3]);
    acc[3][0] = fmaf(h4.w, w4.x, acc[3][0]);
    acc[3][1] = fmaf(h4.w, w4.y, acc[3][1]);
    acc[3][2] = fmaf(h4.w, w4.z, acc[3][2]);
    acc[3][3] = fmaf(h4.w, w4.w, acc[3][3]);
}

// Persistent kernel: 256 blocks x 1024 thr (16 waves, 4/SIMD, 1 block/CU).
// Block = (utile=blockIdx&63 -> 16 u, btile=blockIdx>>6 -> 16 b).
// XCD = blockIdx%8 = utile%8 -> per-XCD weight slice ~2.25MB, L2-resident.
__global__ __launch_bounds__(1024, 4) void lstm_persist(
    const float* __restrict__ xT,     // [SS][FF][64]
    const float* __restrict__ Wh4,    // [1024k][1024u][4]
    const float* __restrict__ Wf4,    // [128k][1024u][4]
    const float* __restrict__ bfb,    // [4][1024]
    float* __restrict__ out,          // [64][512][1024] — also the h ring
    unsigned* flags) {                // [4 btile][64 utile]
    // union: hs (h staged transposed, [16 b][257 float4]) / zl (reduce partials)
    __shared__ __align__(16) float smem[16 * 1028];   // 65.8 KB
    __shared__ float zr[1024];                        // 4 KB
    float4* hs4 = (float4*)smem;
    float*  hsf = smem;
    float*  zl  = smem;

    const int utile = blockIdx.x & 63;
    const int btile = blockIdx.x >> 6;
    const int u0 = utile * 16;
    const int wid  = threadIdx.x >> 6;
    const int lane = threadIdx.x & 63;
    const int u_l  = lane & 15;
    const int bgrp = lane >> 4;
    const int bbase = btile * 16 + bgrp * 4;
    const int k0 = wid * 64;

    // one-time agent fence: flush/inv any stale (poison) L2 lines
    __builtin_amdgcn_fence(__ATOMIC_SEQ_CST, "agent");

    const float* wfx = Wf4 + ((size_t)(wid * 8) * UU + u0 + u_l) * 4;
    const float* whb = Wh4 + ((size_t)k0 * UU + u0 + u_l) * 4;
    unsigned* myflag = &flags[btile * 64 + utile];
    unsigned* gflags = &flags[btile * 64];

    // stage-2 per-thread constants (thread < 256 owns one (b,u))
    float bz0 = 0, bz1 = 0, bz2 = 0, bz3 = 0, creg = 0.0f;
    int s2_zi = 0;
    size_t s2_ob = 0;
    if (threadIdx.x < 256) {
        const int bl = threadIdx.x >> 4, ul = threadIdx.x & 15;
        const int bb = btile * 16 + bl, uu = u0 + ul;
        bz0 = bfb[uu];  bz1 = bfb[uu + UU];
        bz2 = bfb[uu + 2 * UU];  bz3 = bfb[uu + 3 * UU];
        s2_zi = ((bl & 3) * 4) * 64 + (bl >> 2) * 16 + ul;  // zr[(ii*4+g)*64+ln]
        s2_ob = ((size_t)bb * SS) * UU + uu;
    }

    for (int t = 0; t < SS; ++t) {
        float acc[4][4];
#pragma unroll
        for (int i = 0; i < 4; ++i)
#pragma unroll
            for (int g = 0; g < 4; ++g) acc[i][g] = 0.0f;

        // ---- x part (independent of other blocks; overlaps sync shadow) ----
        {
            const float* xp = xT + ((size_t)t * FF + wid * 8) * 64 + bbase;
            const float* wp = wfx;
            float4 hb[8], wb[8];
#pragma unroll
            for (int j = 0; j < 8; ++j) {
                hb[j] = *(const float4*)(xp + j * 64);
                wb[j] = *(const float4*)(wp + (size_t)j * UU * 4);
            }
#pragma unroll
            for (int j = 0; j < 8; ++j) fma16(acc, hb[j], wb[j]);
        }

        if (t > 0) {
            // ---- group sync: 64 threads poll 64 flags (sc1, ~4 lines) ----
            if (threadIdx.x < 64) {
                while (__hip_atomic_load(&gflags[threadIdx.x], __ATOMIC_RELAXED,
                                         __HIP_MEMORY_SCOPE_AGENT) < (unsigned)t)
                    __builtin_amdgcn_s_sleep(2);
            }
            __syncthreads();

            // ---- stage h = out[btile rows][t-1][*] into LDS, transposed ----
            // normal cached loads: address written once (this step) -> never stale
            {
                const float* orow = out + (size_t)(btile * 16) * SS * UU
                                        + (size_t)(t - 1) * UU;
                for (int i = threadIdx.x; i < 4096; i += 1024) {
                    int b_l = i >> 8;          // 0..15
                    int u4 = i & 255;          // float4 index along u(=k)
                    float4 v = *(const float4*)(orow + (size_t)b_l * SS * UU + u4 * 4);
                    hs4[b_l * 257 + u4] = v;
                }
            }
            __syncthreads();

            // ---- h GEMM: wave = k in [k0, k0+64), h from LDS (broadcast) ----
            const float* wp = whb;
            for (int kk = 0; kk < 64; kk += 8) {
                float4 w4[8];
#pragma unroll
                for (int j = 0; j < 8; ++j)
                    w4[j] = *(const float4*)(wp + (size_t)(kk + j) * UU * 4);
                float hb[4][8];
#pragma unroll
                for (int i = 0; i < 4; ++i) {
                    float4 a = *(const float4*)(hsf + (bgrp * 4 + i) * 1028 + k0 + kk);
                    float4 c = *(const float4*)(hsf + (bgrp * 4 + i) * 1028 + k0 + kk + 4);
                    hb[i][0] = a.x; hb[i][1] = a.y; hb[i][2] = a.z; hb[i][3] = a.w;
                    hb[i][4] = c.x; hb[i][5] = c.y; hb[i][6] = c.z; hb[i][7] = c.w;
                }
#pragma unroll
                for (int j = 0; j < 8; ++j)
                    fma16(acc, make_float4(hb[0][j], hb[1][j], hb[2][j], hb[3][j]), w4[j]);
            }
        }

        // hs reads done before zl overwrites the union
        __syncthreads();

        // ---- partials -> LDS, lane-stride-1 (conflict-free) ----
#pragma unroll
        for (int i = 0; i < 4; ++i)
#pragma unroll
            for (int g = 0; g < 4; ++g)
                zl[wid * 1024 + (i * 4 + g) * 64 + lane] = acc[i][g];
        __syncthreads();

        {
            float v = 0.0f;
#pragma unroll
            for (int w = 0; w < 16; ++w) v += zl[w * 1024 + threadIdx.x];
            zr[threadIdx.x] = v;
        }
        __syncthreads();

        // ---- stage 2: gates + state; h(out) store via sc1 (write-through) ----
        if (threadIdx.x < 256) {
            float z0 = zr[s2_zi + 0 * 64] + bz0;
            float z1 = zr[s2_zi + 1 * 64] + bz1;
            float z2 = zr[s2_zi + 2 * 64] + bz2;
            float z3 = zr[s2_zi + 3 * 64] + bz3;

            float iv = sigmoidf_(z0);
            float fv = sigmoidf_(z1);
            float gv = tanhf_(z2);
            float ov = sigmoidf_(z3);

            creg = fv * creg + iv * gv;
            float hv = ov * tanhf_(creg);

            __hip_atomic_store(out + s2_ob + (size_t)t * UU, hv, __ATOMIC_RELAXED,
                               __HIP_MEMORY_SCOPE_AGENT);
        }

        // ---- arrive: syncthreads drains vmcnt (out stores acked), 1 sc1 store ----
        if (t != SS - 1) {
            __syncthreads();
            if (threadIdx.x == 0)
                __hip_atomic_store(myflag, (unsigned)(t + 1), __ATOMIC_RELAXED,
                                   __HIP_MEMORY_SCOPE_AGENT);
        }
    }
}

extern "C" void kernel_launch(void* const* d_in, const int* in_sizes, int n_in,
                              void* d_out, int out_size, void* d_ws, size_t ws_size,
                              hipStream_t stream) {
    const float* x    = (const float*)d_in[0];   // [64,512,128]
    const float* dW   = (const float*)d_in[1];   // [128,512]
    const float* db   = (const float*)d_in[2];   // [512]
    const float* Wx   = (const float*)d_in[3];   // [512,4096]
    const float* Wh   = (const float*)d_in[4];   // [1024,4096]
    const float* bias = (const float*)d_in[5];   // [4096]
    float* out = (float*)d_out;                  // [64,512,1024]

    char* ws = (char*)d_ws;
    size_t off = 0;
    float* Wh4 = (float*)(ws + off); off += (size_t)UU * UU * 4 * 4;   // 16 MB
    float* xT  = (float*)(ws + off); off += (size_t)SS * FF * 64 * 4;  // 16 MB
    float* Wf4 = (float*)(ws + off); off += (size_t)FF * UU * 4 * 4;   // 2 MB
    float* bf  = (float*)(ws + off); off += (size_t)GG * 4;            // 16 KB
    unsigned* flags = (unsigned*)(ws + off);                           // 1 KB

    hipMemsetAsync(flags, 0, 4 * 64 * sizeof(unsigned), stream);
    fuse_w<<<(FF * GG) / 256, 256, 0, stream>>>(dW, Wx, Wf4);
    fuse_b<<<GG / 256, 256, 0, stream>>>(db, Wx, bias, bf);
    repack_wh<<<(UU * GG) / 256, 256, 0, stream>>>(Wh, Wh4);
    transpose_x<<<SS, 256, 0, stream>>>(x, xT);

    void* args[] = {(void*)&xT, (void*)&Wh4, (void*)&Wf4, (void*)&bf, (void*)&out,
                    (void*)&flags};
    hipLaunchCooperativeKernel((void*)lstm_persist, dim3(NBLK), dim3(1024), args, 0, stream);
}